// Round 4
// baseline (412.512 us; speedup 1.0000x reference)
//
#include <hip/hip_runtime.h>
#include <hip/hip_bf16.h>
#include <math.h>

typedef __bf16 bf16_t;
typedef bf16_t bf16x8 __attribute__((ext_vector_type(8)));
typedef float f32x4 __attribute__((ext_vector_type(4)));

// ---------------- async global->LDS (16B per lane) ----------------
__device__ __forceinline__ void g2l16(const bf16_t* g, bf16_t* l) {
    __builtin_amdgcn_global_load_lds(
        (const __attribute__((address_space(1))) void*)g,
        (__attribute__((address_space(3))) void*)l, 16, 0, 0);
}

// ---------------- fused prep: probe + x->bf16 + dequant W1/W2 + biases ---------
__global__ void prep_all(const void* __restrict__ x,
                         const void* __restrict__ cb1, const int* __restrict__ idx1,
                         const void* __restrict__ b1,
                         const void* __restrict__ cb2, const int* __restrict__ idx2,
                         const void* __restrict__ b2,
                         bf16_t* __restrict__ xb, bf16_t* __restrict__ w1b,
                         bf16_t* __restrict__ w2b, float* __restrict__ b1f,
                         float* __restrict__ b2f, int* __restrict__ flag, int M) {
    __shared__ int s_bad;
    if (threadIdx.x == 0) s_bad = 0;
    __syncthreads();
    const unsigned short* xu = (const unsigned short*)x;
    int cnt = 0;
    for (int i = threadIdx.x; i < 8192; i += 256)
        cnt += (((xu[i] >> 7) & 0xFF) >= 0x88);
    atomicAdd(&s_bad, cnt);
    __syncthreads();
    const int f32 = (s_bad > 4);
    if (blockIdx.x == 0 && threadIdx.x == 0) flag[0] = f32;

    const int T0 = (M * 1024) / 8;
    const int T1 = 4096 * 128;
    const int T2 = 1024 * 512;
    const int TB = (4096 + 1024) / 8;
    const int total = T0 + T1 + T2 + TB;
    const int t = blockIdx.x * 256 + threadIdx.x;
    const int stride = gridDim.x * 256;

    for (int i = t; i < total; i += stride) {
        if (i < T0) {
            bf16x8 o;
            if (f32) {
                const float4* p = (const float4*)x;
                float4 a = p[2 * i], b = p[2 * i + 1];
                o[0] = (bf16_t)a.x; o[1] = (bf16_t)a.y; o[2] = (bf16_t)a.z; o[3] = (bf16_t)a.w;
                o[4] = (bf16_t)b.x; o[5] = (bf16_t)b.y; o[6] = (bf16_t)b.z; o[7] = (bf16_t)b.w;
            } else {
                o = ((const bf16x8*)x)[i];
            }
            *(bf16x8*)(xb + (size_t)i * 8) = o;
        } else if (i < T0 + T1 + T2) {
            int g2 = (i >= T0 + T1);
            int ii = g2 ? (i - T0 - T1) : (i - T0);
            int rows = g2 ? 1024 : 4096;
            int logsub = g2 ? 9 : 7;
            int sub = 1 << logsub;
            const int* idx = g2 ? idx2 : idx1;
            const void* cb = g2 ? cb2 : cb1;
            bf16_t* W = g2 ? w2b : w1b;
            int r = ii >> logsub;
            int col = (ii & (sub - 1)) << 3;
            int c = col >> logsub;
            int j = col & (sub - 1);
            int code = idx[c * rows + r];
            size_t src = ((size_t)(c * 256 + code) << logsub) + j;
            bf16x8 o;
            if (f32) {
                const float* s = (const float*)cb + src;
                float4 a = *(const float4*)s;
                float4 b = *(const float4*)(s + 4);
                o[0] = (bf16_t)a.x; o[1] = (bf16_t)a.y; o[2] = (bf16_t)a.z; o[3] = (bf16_t)a.w;
                o[4] = (bf16_t)b.x; o[5] = (bf16_t)b.y; o[6] = (bf16_t)b.z; o[7] = (bf16_t)b.w;
            } else {
                o = *(const bf16x8*)((const bf16_t*)cb + src);
            }
            *(bf16x8*)(W + (size_t)r * ((size_t)sub << 3) + col) = o;
        } else {
            int g = i - (T0 + T1 + T2);
#pragma unroll
            for (int j = 0; j < 8; ++j) {
                int e = g * 8 + j;
                float v;
                const void* src = (e < 4096) ? b1 : b2;
                int k = (e < 4096) ? e : e - 4096;
                v = f32 ? ((const float*)src)[k] : (float)(((const bf16_t*)src)[k]);
                if (e < 4096) b1f[k] = v; else b2f[k] = v;
            }
        }
    }
}

// ---------------- GEMM: C[m,n] = sum_k A[m,k]*Bw[n,k] + bias[n] (opt gelu) ------
// 128x128 tile, BK=64, 4 waves 2x2, 16x16x32 MFMA.
// A: staged via global_load_lds into XOR-swizzled LDS (conflict-free, R3).
// B: loaded DIRECTLY global->VGPR — a lane's B-frag is 16 contiguous bytes of
//    Bw ([N,K] row-major), so LDS staging is pure overhead. Halves LDS traffic
//    and the barrier-coupled g2l16 count; B-tiles stay hot in L1/L2.
//    Next-iter B-frags prefetched during MFMA (VGPR loads aren't barrier-bound).
// Block swizzle: bn-groups of 8 so a group's B working set is 2 MB (L2-sized).
template <bool GELU, bool DYNOUT>
__global__ __launch_bounds__(256, 2)
void gemm_bt(const bf16_t* __restrict__ A, const bf16_t* __restrict__ Bw,
             const float* __restrict__ bias,
             bf16_t* __restrict__ obf, float* __restrict__ of32,
             int M, int N, int K, const int* __restrict__ flag) {
    __shared__ __attribute__((aligned(16))) bf16_t sA[128 * 64];

    const int tid = threadIdx.x;

    // group-major swizzle: 8 bn-columns x all bm per group (identity when gridDim.x==8)
    const int l = blockIdx.y * gridDim.x + blockIdx.x;
    const int grp = l / (8 * gridDim.y);
    const int rem = l % (8 * gridDim.y);
    const int bn = (grp * 8 + (rem & 7)) << 7;
    const int bm = (rem >> 3) << 7;

    // A staging: thread t -> slot t (16B); row = p*32 + t>>3, swizzled k-chunk
    const int row0 = tid >> 3;
    const int kc0 = ((tid & 7) - row0) & 7;
    const bf16_t* gA = A + (size_t)(bm + row0) * K + kc0 * 8;
    bf16_t* lA = sA + tid * 8;
    const size_t pskip = (size_t)32 * K;

    const int lane = tid & 63;
    const int wave = tid >> 6;
    const int quad = lane >> 4;
    const int lr = lane & 15;
    const int wm = (wave & 1) << 6;
    const int wn = (wave >> 1) << 6;

    const int arow = wm + lr;
    const bf16x8* pA0 = (const bf16x8*)(sA + arow * 64 + ((quad + arow) & 7) * 8);
    const bf16x8* pA1 = (const bf16x8*)(sA + arow * 64 + ((quad + 4 + arow) & 7) * 8);

    // B direct-from-global fragment base: row (bn+wn+ni*16+lr), cols quad*8..
    const bf16_t* gB = Bw + (size_t)(bn + wn + lr) * K + quad * 8;
    const size_t bstep = (size_t)16 * K;

    f32x4 acc[4][4] = {};

    bf16x8 b0[4], b1[4];
#pragma unroll
    for (int ni = 0; ni < 4; ++ni) {
        b0[ni] = *(const bf16x8*)(gB + ni * bstep);
        b1[ni] = *(const bf16x8*)(gB + ni * bstep + 32);
    }

    for (int k0 = 0; k0 < K; k0 += 64) {
#pragma unroll
        for (int p = 0; p < 4; ++p) g2l16(gA + p * pskip + k0, lA + p * 2048);
        __syncthreads();

        // prefetch next iteration's B while this iteration's MFMAs run
        bf16x8 nb0[4], nb1[4];
        if (k0 + 64 < K) {
#pragma unroll
            for (int ni = 0; ni < 4; ++ni) {
                nb0[ni] = *(const bf16x8*)(gB + ni * bstep + k0 + 64);
                nb1[ni] = *(const bf16x8*)(gB + ni * bstep + k0 + 96);
            }
        }

        bf16x8 af[4];
#pragma unroll
        for (int i = 0; i < 4; ++i) af[i] = pA0[i * 128];
#pragma unroll
        for (int mi = 0; mi < 4; ++mi)
#pragma unroll
            for (int ni = 0; ni < 4; ++ni)
                acc[mi][ni] = __builtin_amdgcn_mfma_f32_16x16x32_bf16(
                    af[mi], b0[ni], acc[mi][ni], 0, 0, 0);
#pragma unroll
        for (int i = 0; i < 4; ++i) af[i] = pA1[i * 128];
#pragma unroll
        for (int mi = 0; mi < 4; ++mi)
#pragma unroll
            for (int ni = 0; ni < 4; ++ni)
                acc[mi][ni] = __builtin_amdgcn_mfma_f32_16x16x32_bf16(
                    af[mi], b1[ni], acc[mi][ni], 0, 0, 0);
        __syncthreads();

#pragma unroll
        for (int ni = 0; ni < 4; ++ni) { b0[ni] = nb0[ni]; b1[ni] = nb1[ni]; }
    }

    const int outf32 = DYNOUT ? *flag : 0;
#pragma unroll
    for (int mi = 0; mi < 4; ++mi) {
#pragma unroll
        for (int ni = 0; ni < 4; ++ni) {
            const int n = bn + wn + ni * 16 + lr;
            const float bs = bias[n];
            f32x4 v = acc[mi][ni];
#pragma unroll
            for (int r = 0; r < 4; ++r) {
                const int m = bm + wm + mi * 16 + quad * 4 + r;
                float val = v[r] + bs;
                if (GELU) val = 0.5f * val * (1.0f + erff(val * 0.70710678118654752f));
                const size_t o = (size_t)m * N + n;
                if (DYNOUT) {
                    if (outf32) of32[o] = val;
                    else        obf[o] = (bf16_t)val;
                } else {
                    obf[o] = (bf16_t)val;
                }
            }
        }
    }
}

// ---------------- launch ----------------
extern "C" void kernel_launch(void* const* d_in, const int* in_sizes, int n_in,
                              void* d_out, int out_size, void* d_ws, size_t ws_size,
                              hipStream_t stream) {
    const void* x   = d_in[0];
    const void* cb1 = d_in[1];
    const int*  idx1 = (const int*)d_in[2];
    const void* b1  = d_in[3];
    const void* cb2 = d_in[4];
    const int*  idx2 = (const int*)d_in[5];
    const void* b2  = d_in[6];

    const int D = 1024, H = 4096;
    const int M = in_sizes[0] / D;     // 8192

    char* ws = (char*)d_ws;
    bf16_t* xb  = (bf16_t*)ws;                                   // M*D bf16 (16 MB)
    bf16_t* w1b = (bf16_t*)(ws + (size_t)M * D * 2);             // H*D bf16 (8 MB)
    bf16_t* hb  = (bf16_t*)((char*)w1b + (size_t)H * D * 2);     // M*H bf16 (64 MB)
    bf16_t* w2b = (bf16_t*)((char*)hb + (size_t)M * H * 2);      // D*H bf16 (8 MB)
    float*  b1f = (float*)((char*)w2b + (size_t)D * H * 2);      // H f32
    float*  b2f = b1f + H;                                       // D f32
    int*    flag = (int*)(b2f + D);

    prep_all<<<2048, 256, 0, stream>>>(x, cb1, idx1, b1, cb2, idx2, b2,
                                       xb, w1b, w2b, b1f, b2f, flag, M);

    dim3 g1(H / 128, M / 128);   // (32, 64)
    gemm_bt<true, false><<<g1, 256, 0, stream>>>(xb, w1b, b1f, hb, nullptr, M, H, D, flag);

    dim3 g2(D / 128, M / 128);   // (8, 64)
    gemm_bt<false, true><<<g2, 256, 0, stream>>>(hb, w2b, b2f, (bf16_t*)d_out, (float*)d_out, M, D, H, flag);
}

// Round 5
// 267.842 us; speedup vs baseline: 1.5401x; 1.5401x over previous
//
#include <hip/hip_runtime.h>
#include <hip/hip_bf16.h>
#include <math.h>

typedef __bf16 bf16_t;
typedef bf16_t bf16x8 __attribute__((ext_vector_type(8)));
typedef float f32x4 __attribute__((ext_vector_type(4)));

// ---------------- async global->LDS (16B per lane) ----------------
__device__ __forceinline__ void g2l16(const bf16_t* g, bf16_t* l) {
    __builtin_amdgcn_global_load_lds(
        (const __attribute__((address_space(1))) void*)g,
        (__attribute__((address_space(3))) void*)l, 16, 0, 0);
}

// ---------------- fused prep: probe + x->bf16 + dequant W1/W2 + biases ---------
__global__ void prep_all(const void* __restrict__ x,
                         const void* __restrict__ cb1, const int* __restrict__ idx1,
                         const void* __restrict__ b1,
                         const void* __restrict__ cb2, const int* __restrict__ idx2,
                         const void* __restrict__ b2,
                         bf16_t* __restrict__ xb, bf16_t* __restrict__ w1b,
                         bf16_t* __restrict__ w2b, float* __restrict__ b1f,
                         float* __restrict__ b2f, int* __restrict__ flag, int M) {
    __shared__ int s_bad;
    if (threadIdx.x == 0) s_bad = 0;
    __syncthreads();
    const unsigned short* xu = (const unsigned short*)x;
    int cnt = 0;
    for (int i = threadIdx.x; i < 8192; i += 256)
        cnt += (((xu[i] >> 7) & 0xFF) >= 0x88);
#pragma unroll
    for (int o = 32; o > 0; o >>= 1) cnt += __shfl_down(cnt, o, 64);
    if ((threadIdx.x & 63) == 0) atomicAdd(&s_bad, cnt);
    __syncthreads();
    const int f32 = (s_bad > 4);
    if (blockIdx.x == 0 && threadIdx.x == 0) flag[0] = f32;

    const int T0 = (M * 1024) / 8;
    const int T1 = 4096 * 128;
    const int T2 = 1024 * 512;
    const int TB = (4096 + 1024) / 8;
    const int total = T0 + T1 + T2 + TB;
    const int t = blockIdx.x * 256 + threadIdx.x;
    const int stride = gridDim.x * 256;

    for (int i = t; i < total; i += stride) {
        if (i < T0) {
            bf16x8 o;
            if (f32) {
                const float4* p = (const float4*)x;
                float4 a = p[2 * i], b = p[2 * i + 1];
                o[0] = (bf16_t)a.x; o[1] = (bf16_t)a.y; o[2] = (bf16_t)a.z; o[3] = (bf16_t)a.w;
                o[4] = (bf16_t)b.x; o[5] = (bf16_t)b.y; o[6] = (bf16_t)b.z; o[7] = (bf16_t)b.w;
            } else {
                o = ((const bf16x8*)x)[i];
            }
            *(bf16x8*)(xb + (size_t)i * 8) = o;
        } else if (i < T0 + T1 + T2) {
            int g2 = (i >= T0 + T1);
            int ii = g2 ? (i - T0 - T1) : (i - T0);
            int rows = g2 ? 1024 : 4096;
            int logsub = g2 ? 9 : 7;
            int sub = 1 << logsub;
            const int* idx = g2 ? idx2 : idx1;
            const void* cb = g2 ? cb2 : cb1;
            bf16_t* W = g2 ? w2b : w1b;
            int r = ii >> logsub;
            int col = (ii & (sub - 1)) << 3;
            int c = col >> logsub;
            int j = col & (sub - 1);
            int code = idx[c * rows + r];
            size_t src = ((size_t)(c * 256 + code) << logsub) + j;
            bf16x8 o;
            if (f32) {
                const float* s = (const float*)cb + src;
                float4 a = *(const float4*)s;
                float4 b = *(const float4*)(s + 4);
                o[0] = (bf16_t)a.x; o[1] = (bf16_t)a.y; o[2] = (bf16_t)a.z; o[3] = (bf16_t)a.w;
                o[4] = (bf16_t)b.x; o[5] = (bf16_t)b.y; o[6] = (bf16_t)b.z; o[7] = (bf16_t)b.w;
            } else {
                o = *(const bf16x8*)((const bf16_t*)cb + src);
            }
            *(bf16x8*)(W + (size_t)r * ((size_t)sub << 3) + col) = o;
        } else {
            int g = i - (T0 + T1 + T2);
#pragma unroll
            for (int j = 0; j < 8; ++j) {
                int e = g * 8 + j;
                float v;
                const void* src = (e < 4096) ? b1 : b2;
                int k = (e < 4096) ? e : e - 4096;
                v = f32 ? ((const float*)src)[k] : (float)(((const bf16_t*)src)[k]);
                if (e < 4096) b1f[k] = v; else b2f[k] = v;
            }
        }
    }
}

// ---------------- GEMM: C[m,n] = sum_k A[m,k]*Bw[n,k] + bias[n] (opt gelu) ------
// 128x128 tile, BK=128 (half the barrier drains of BK=64; LDS 64KB is free since
// we're already reg-limited to 2 blocks/CU). A and B staged via global_load_lds
// into XOR-swizzled LDS (16-chunk swizzle, conflict-free; R3 measured 0).
// XCD-band swizzle: xcd = l&7 (round-robin dispatch), each XCD owns a contiguous
// bm-band (8 tiles) and sweeps bn; the 8 blocks sharing a B-tile are consecutive
// on the SAME XCD -> per-XCD L2 holds A-band (2MB GEMM1) + one B-tile.
template <bool GELU, bool DYNOUT>
__global__ __launch_bounds__(256, 2)
void gemm_bt(const bf16_t* __restrict__ A, const bf16_t* __restrict__ Bw,
             const float* __restrict__ bias,
             bf16_t* __restrict__ obf, float* __restrict__ of32,
             int M, int N, int K, const int* __restrict__ flag) {
    __shared__ __attribute__((aligned(16))) bf16_t sA[128 * 128];
    __shared__ __attribute__((aligned(16))) bf16_t sB[128 * 128];

    const int tid = threadIdx.x;

    // XCD-band swizzle (gridDim.y divisible by 8)
    const int l = blockIdx.y * gridDim.x + blockIdx.x;
    const int xcd = l & 7;
    const int i = l >> 3;
    const int per = gridDim.y >> 3;              // bm-tiles per band
    const int bm = (xcd * per + (i % per)) << 7;
    const int bn = (i / per) << 7;

    // staging: pass p stages 16 rows; thread t: row = p*16 + (t>>4),
    // k-chunk kc = ((t&15) - (t>>4)) & 15 (pass-invariant), slot t (16B)
    const int row0 = tid >> 4;                   // 0..15
    const int kc0 = ((tid & 15) - row0) & 15;
    const bf16_t* gA = A + (size_t)(bm + row0) * K + kc0 * 8;
    const bf16_t* gB = Bw + (size_t)(bn + row0) * K + kc0 * 8;
    bf16_t* lA = sA + tid * 8;
    bf16_t* lB = sB + tid * 8;
    const size_t pskip = (size_t)16 * K;

    const int lane = tid & 63;
    const int wave = tid >> 6;
    const int quad = lane >> 4;
    const int lr = lane & 15;
    const int wm = (wave & 1) << 6;
    const int wn = (wave >> 1) << 6;
    const int arow = wm + lr;
    const int brow = wn + lr;

    f32x4 acc[4][4] = {};

    for (int k0 = 0; k0 < K; k0 += 128) {
#pragma unroll
        for (int p = 0; p < 8; ++p) g2l16(gA + p * pskip + k0, lA + p * 2048);
#pragma unroll
        for (int p = 0; p < 8; ++p) g2l16(gB + p * pskip + k0, lB + p * 2048);
        __syncthreads();

#pragma unroll
        for (int s = 0; s < 4; ++s) {           // 4 sub-steps of K=32
            bf16x8 af[4], bf[4];
#pragma unroll
            for (int f = 0; f < 4; ++f) {
                const int ar = arow + f * 16;
                const int br = brow + f * 16;
                af[f] = *(const bf16x8*)(sA + ar * 128 + (((s * 4 + quad + ar) & 15) << 3));
                bf[f] = *(const bf16x8*)(sB + br * 128 + (((s * 4 + quad + br) & 15) << 3));
            }
#pragma unroll
            for (int mi = 0; mi < 4; ++mi)
#pragma unroll
                for (int ni = 0; ni < 4; ++ni)
                    acc[mi][ni] = __builtin_amdgcn_mfma_f32_16x16x32_bf16(
                        af[mi], bf[ni], acc[mi][ni], 0, 0, 0);
        }
        __syncthreads();
    }

    const int outf32 = DYNOUT ? *flag : 0;
#pragma unroll
    for (int mi = 0; mi < 4; ++mi) {
#pragma unroll
        for (int ni = 0; ni < 4; ++ni) {
            const int n = bn + wn + ni * 16 + lr;
            const float bs = bias[n];
            f32x4 v = acc[mi][ni];
#pragma unroll
            for (int r = 0; r < 4; ++r) {
                const int m = bm + wm + mi * 16 + quad * 4 + r;
                float val = v[r] + bs;
                if (GELU) val = 0.5f * val * (1.0f + erff(val * 0.70710678118654752f));
                const size_t o = (size_t)m * N + n;
                if (DYNOUT) {
                    if (outf32) of32[o] = val;
                    else        obf[o] = (bf16_t)val;
                } else {
                    obf[o] = (bf16_t)val;
                }
            }
        }
    }
}

// ---------------- launch ----------------
extern "C" void kernel_launch(void* const* d_in, const int* in_sizes, int n_in,
                              void* d_out, int out_size, void* d_ws, size_t ws_size,
                              hipStream_t stream) {
    const void* x   = d_in[0];
    const void* cb1 = d_in[1];
    const int*  idx1 = (const int*)d_in[2];
    const void* b1  = d_in[3];
    const void* cb2 = d_in[4];
    const int*  idx2 = (const int*)d_in[5];
    const void* b2  = d_in[6];

    const int D = 1024, H = 4096;
    const int M = in_sizes[0] / D;     // 8192

    char* ws = (char*)d_ws;
    bf16_t* xb  = (bf16_t*)ws;                                   // M*D bf16 (16 MB)
    bf16_t* w1b = (bf16_t*)(ws + (size_t)M * D * 2);             // H*D bf16 (8 MB)
    bf16_t* hb  = (bf16_t*)((char*)w1b + (size_t)H * D * 2);     // M*H bf16 (64 MB)
    bf16_t* w2b = (bf16_t*)((char*)hb + (size_t)M * H * 2);      // D*H bf16 (8 MB)
    float*  b1f = (float*)((char*)w2b + (size_t)D * H * 2);      // H f32
    float*  b2f = b1f + H;                                       // D f32
    int*    flag = (int*)(b2f + D);

    prep_all<<<2048, 256, 0, stream>>>(x, cb1, idx1, b1, cb2, idx2, b2,
                                       xb, w1b, w2b, b1f, b2f, flag, M);

    dim3 g1(H / 128, M / 128);   // (32, 64)
    gemm_bt<true, false><<<g1, 256, 0, stream>>>(xb, w1b, b1f, hb, nullptr, M, H, D, flag);

    dim3 g2(D / 128, M / 128);   // (8, 64)
    gemm_bt<false, true><<<g2, 256, 0, stream>>>(hb, w2b, b2f, (bf16_t*)d_out, (float*)d_out, M, D, H, flag);
}

// Round 6
// 260.233 us; speedup vs baseline: 1.5852x; 1.0292x over previous
//
#include <hip/hip_runtime.h>
#include <hip/hip_bf16.h>
#include <math.h>

typedef __bf16 bf16_t;
typedef bf16_t bf16x8 __attribute__((ext_vector_type(8)));
typedef float f32x4 __attribute__((ext_vector_type(4)));

// ---------------- async global->LDS (16B per lane) ----------------
__device__ __forceinline__ void g2l16(const bf16_t* g, bf16_t* l) {
    __builtin_amdgcn_global_load_lds(
        (const __attribute__((address_space(1))) void*)g,
        (__attribute__((address_space(3))) void*)l, 16, 0, 0);
}

// ---------------- fused prep: probe + x->bf16 + dequant W1/W2 + biases ---------
__global__ void prep_all(const void* __restrict__ x,
                         const void* __restrict__ cb1, const int* __restrict__ idx1,
                         const void* __restrict__ b1,
                         const void* __restrict__ cb2, const int* __restrict__ idx2,
                         const void* __restrict__ b2,
                         bf16_t* __restrict__ xb, bf16_t* __restrict__ w1b,
                         bf16_t* __restrict__ w2b, float* __restrict__ b1f,
                         float* __restrict__ b2f, int* __restrict__ flag, int M) {
    __shared__ int s_bad;
    if (threadIdx.x == 0) s_bad = 0;
    __syncthreads();
    const unsigned short* xu = (const unsigned short*)x;
    int cnt = 0;
    for (int i = threadIdx.x; i < 8192; i += 256)
        cnt += (((xu[i] >> 7) & 0xFF) >= 0x88);
#pragma unroll
    for (int o = 32; o > 0; o >>= 1) cnt += __shfl_down(cnt, o, 64);
    if ((threadIdx.x & 63) == 0) atomicAdd(&s_bad, cnt);
    __syncthreads();
    const int f32 = (s_bad > 4);
    if (blockIdx.x == 0 && threadIdx.x == 0) flag[0] = f32;

    const int T0 = (M * 1024) / 8;
    const int T1 = 4096 * 128;
    const int T2 = 1024 * 512;
    const int TB = (4096 + 1024) / 8;
    const int total = T0 + T1 + T2 + TB;
    const int t = blockIdx.x * 256 + threadIdx.x;
    const int stride = gridDim.x * 256;

    for (int i = t; i < total; i += stride) {
        if (i < T0) {
            bf16x8 o;
            if (f32) {
                const float4* p = (const float4*)x;
                float4 a = p[2 * i], b = p[2 * i + 1];
                o[0] = (bf16_t)a.x; o[1] = (bf16_t)a.y; o[2] = (bf16_t)a.z; o[3] = (bf16_t)a.w;
                o[4] = (bf16_t)b.x; o[5] = (bf16_t)b.y; o[6] = (bf16_t)b.z; o[7] = (bf16_t)b.w;
            } else {
                o = ((const bf16x8*)x)[i];
            }
            *(bf16x8*)(xb + (size_t)i * 8) = o;
        } else if (i < T0 + T1 + T2) {
            int g2 = (i >= T0 + T1);
            int ii = g2 ? (i - T0 - T1) : (i - T0);
            int rows = g2 ? 1024 : 4096;
            int logsub = g2 ? 9 : 7;
            int sub = 1 << logsub;
            const int* idx = g2 ? idx2 : idx1;
            const void* cb = g2 ? cb2 : cb1;
            bf16_t* W = g2 ? w2b : w1b;
            int r = ii >> logsub;
            int col = (ii & (sub - 1)) << 3;
            int c = col >> logsub;
            int j = col & (sub - 1);
            int code = idx[c * rows + r];
            size_t src = ((size_t)(c * 256 + code) << logsub) + j;
            bf16x8 o;
            if (f32) {
                const float* s = (const float*)cb + src;
                float4 a = *(const float4*)s;
                float4 b = *(const float4*)(s + 4);
                o[0] = (bf16_t)a.x; o[1] = (bf16_t)a.y; o[2] = (bf16_t)a.z; o[3] = (bf16_t)a.w;
                o[4] = (bf16_t)b.x; o[5] = (bf16_t)b.y; o[6] = (bf16_t)b.z; o[7] = (bf16_t)b.w;
            } else {
                o = *(const bf16x8*)((const bf16_t*)cb + src);
            }
            *(bf16x8*)(W + (size_t)r * ((size_t)sub << 3) + col) = o;
        } else {
            int g = i - (T0 + T1 + T2);
#pragma unroll
            for (int j = 0; j < 8; ++j) {
                int e = g * 8 + j;
                float v;
                const void* src = (e < 4096) ? b1 : b2;
                int k = (e < 4096) ? e : e - 4096;
                v = f32 ? ((const float*)src)[k] : (float)(((const bf16_t*)src)[k]);
                if (e < 4096) b1f[k] = v; else b2f[k] = v;
            }
        }
    }
}

// ---------------- GEMM: C[m,n] = sum_k A[m,k]*Bw[n,k] + bias[n] (opt gelu) ------
// R3 inner structure (measured 0 conflicts, VALUBusy 15): BK=64, 8-chunk XOR
// swizzle on 64-wide LDS rows, precomputed frag pointers + immediate offsets.
// NF = n-frags per wave (wave tile 64 x NF*16). NF=8 -> block 128x256, 25% less
// LDS bytes/FLOP (the binding pipe per R3 model). NF=4 = R3 config for GEMM2
// (N=1024 can't fill the grid at 256-wide tiles).
// XCD-band swizzle kept from R5: FETCH 266 -> 66 MB measured.
template <int NF, bool GELU, bool DYNOUT>
__global__ __launch_bounds__(256, 2)
void gemm_bt(const bf16_t* __restrict__ A, const bf16_t* __restrict__ Bw,
             const float* __restrict__ bias,
             bf16_t* __restrict__ obf, float* __restrict__ of32,
             int M, int N, int K, const int* __restrict__ flag) {
    constexpr int BN = NF * 32;                 // 128 or 256
    __shared__ __attribute__((aligned(16))) bf16_t sA[128 * 64];
    __shared__ __attribute__((aligned(16))) bf16_t sB[BN * 64];

    const int tid = threadIdx.x;

    // XCD-band swizzle (gridDim.y divisible by 8): xcd = l&7 owns a contiguous
    // bm-band and sweeps bn; blocks sharing a B-tile are consecutive on one XCD.
    const int l = blockIdx.y * gridDim.x + blockIdx.x;
    const int xcd = l & 7;
    const int i = l >> 3;
    const int per = gridDim.y >> 3;             // bm-tiles per band
    const int bm = (xcd * per + (i % per)) << 7;
    const int bn = (i / per) * BN;

    // staging: thread t -> slot t (16B); row = p*32 + t>>3, swizzled k-chunk
    const int row0 = tid >> 3;                  // 0..31
    const int kc0 = ((tid & 7) - row0) & 7;     // pass-invariant (32 % 8 == 0)
    const bf16_t* gA = A + (size_t)(bm + row0) * K + kc0 * 8;
    const bf16_t* gB = Bw + (size_t)(bn + row0) * K + kc0 * 8;
    bf16_t* lA = sA + tid * 8;
    bf16_t* lB = sB + tid * 8;
    const size_t pskip = (size_t)32 * K;

    const int lane = tid & 63;
    const int wave = tid >> 6;
    const int quad = lane >> 4;
    const int lr = lane & 15;
    const int wm = (wave & 1) << 6;             // 0,64
    const int wn = (wave >> 1) * (NF * 16);     // 0, NF*16

    const int arow = wm + lr;
    const int brow = wn + lr;
    const bf16x8* pA0 = (const bf16x8*)(sA + arow * 64 + ((quad + arow) & 7) * 8);
    const bf16x8* pA1 = (const bf16x8*)(sA + arow * 64 + ((quad + 4 + arow) & 7) * 8);
    const bf16x8* pB0 = (const bf16x8*)(sB + brow * 64 + ((quad + brow) & 7) * 8);
    const bf16x8* pB1 = (const bf16x8*)(sB + brow * 64 + ((quad + 4 + brow) & 7) * 8);

    f32x4 acc[4][NF] = {};

    for (int k0 = 0; k0 < K; k0 += 64) {
#pragma unroll
        for (int p = 0; p < 4; ++p) g2l16(gA + p * pskip + k0, lA + p * 2048);
#pragma unroll
        for (int p = 0; p < BN / 32; ++p) g2l16(gB + p * pskip + k0, lB + p * 2048);
        __syncthreads();

        bf16x8 af[4], bf[NF];
#pragma unroll
        for (int f = 0; f < 4; ++f) af[f] = pA0[f * 128];     // +16 rows
#pragma unroll
        for (int f = 0; f < NF; ++f) bf[f] = pB0[f * 128];
#pragma unroll
        for (int mi = 0; mi < 4; ++mi)
#pragma unroll
            for (int ni = 0; ni < NF; ++ni)
                acc[mi][ni] = __builtin_amdgcn_mfma_f32_16x16x32_bf16(
                    af[mi], bf[ni], acc[mi][ni], 0, 0, 0);
#pragma unroll
        for (int f = 0; f < 4; ++f) af[f] = pA1[f * 128];
#pragma unroll
        for (int f = 0; f < NF; ++f) bf[f] = pB1[f * 128];
#pragma unroll
        for (int mi = 0; mi < 4; ++mi)
#pragma unroll
            for (int ni = 0; ni < NF; ++ni)
                acc[mi][ni] = __builtin_amdgcn_mfma_f32_16x16x32_bf16(
                    af[mi], bf[ni], acc[mi][ni], 0, 0, 0);
        __syncthreads();
    }

    const int outf32 = DYNOUT ? *flag : 0;
#pragma unroll
    for (int mi = 0; mi < 4; ++mi) {
#pragma unroll
        for (int ni = 0; ni < NF; ++ni) {
            const int n = bn + wn + ni * 16 + lr;
            const float bs = bias[n];
            f32x4 v = acc[mi][ni];
#pragma unroll
            for (int r = 0; r < 4; ++r) {
                const int m = bm + wm + mi * 16 + quad * 4 + r;
                float val = v[r] + bs;
                if (GELU) val = 0.5f * val * (1.0f + erff(val * 0.70710678118654752f));
                const size_t o = (size_t)m * N + n;
                if (DYNOUT) {
                    if (outf32) of32[o] = val;
                    else        obf[o] = (bf16_t)val;
                } else {
                    obf[o] = (bf16_t)val;
                }
            }
        }
    }
}

// ---------------- launch ----------------
extern "C" void kernel_launch(void* const* d_in, const int* in_sizes, int n_in,
                              void* d_out, int out_size, void* d_ws, size_t ws_size,
                              hipStream_t stream) {
    const void* x   = d_in[0];
    const void* cb1 = d_in[1];
    const int*  idx1 = (const int*)d_in[2];
    const void* b1  = d_in[3];
    const void* cb2 = d_in[4];
    const int*  idx2 = (const int*)d_in[5];
    const void* b2  = d_in[6];

    const int D = 1024, H = 4096;
    const int M = in_sizes[0] / D;     // 8192

    char* ws = (char*)d_ws;
    bf16_t* xb  = (bf16_t*)ws;                                   // M*D bf16 (16 MB)
    bf16_t* w1b = (bf16_t*)(ws + (size_t)M * D * 2);             // H*D bf16 (8 MB)
    bf16_t* hb  = (bf16_t*)((char*)w1b + (size_t)H * D * 2);     // M*H bf16 (64 MB)
    bf16_t* w2b = (bf16_t*)((char*)hb + (size_t)M * H * 2);      // D*H bf16 (8 MB)
    float*  b1f = (float*)((char*)w2b + (size_t)D * H * 2);      // H f32
    float*  b2f = b1f + H;                                       // D f32
    int*    flag = (int*)(b2f + D);

    prep_all<<<2048, 256, 0, stream>>>(x, cb1, idx1, b1, cb2, idx2, b2,
                                       xb, w1b, w2b, b1f, b2f, flag, M);

    dim3 g1(H / 256, M / 128);   // (16, 64) — NF=8, block 128x256
    gemm_bt<8, true, false><<<g1, 256, 0, stream>>>(xb, w1b, b1f, hb, nullptr, M, H, D, flag);

    dim3 g2(D / 128, M / 128);   // (8, 64) — NF=4, R3 config
    gemm_bt<4, false, true><<<g2, 256, 0, stream>>>(hb, w2b, b2f, (bf16_t*)d_out, (float*)d_out, M, D, H, flag);
}

// Round 7
// 252.482 us; speedup vs baseline: 1.6338x; 1.0307x over previous
//
#include <hip/hip_runtime.h>
#include <hip/hip_bf16.h>
#include <math.h>

typedef __bf16 bf16_t;
typedef bf16_t bf16x8 __attribute__((ext_vector_type(8)));
typedef float f32x4 __attribute__((ext_vector_type(4)));

// ---------------- async global->LDS (16B per lane) ----------------
__device__ __forceinline__ void g2l16(const bf16_t* g, bf16_t* l) {
    __builtin_amdgcn_global_load_lds(
        (const __attribute__((address_space(1))) void*)g,
        (__attribute__((address_space(3))) void*)l, 16, 0, 0);
}

// ---------------- fused prep: probe + x->bf16 + dequant W1/W2 + biases ---------
__global__ void prep_all(const void* __restrict__ x,
                         const void* __restrict__ cb1, const int* __restrict__ idx1,
                         const void* __restrict__ b1,
                         const void* __restrict__ cb2, const int* __restrict__ idx2,
                         const void* __restrict__ b2,
                         bf16_t* __restrict__ xb, bf16_t* __restrict__ w1b,
                         bf16_t* __restrict__ w2b, float* __restrict__ b1f,
                         float* __restrict__ b2f, int* __restrict__ flag, int M) {
    __shared__ int s_bad;
    if (threadIdx.x == 0) s_bad = 0;
    __syncthreads();
    const unsigned short* xu = (const unsigned short*)x;
    int cnt = 0;
    for (int i = threadIdx.x; i < 8192; i += 256)
        cnt += (((xu[i] >> 7) & 0xFF) >= 0x88);
#pragma unroll
    for (int o = 32; o > 0; o >>= 1) cnt += __shfl_down(cnt, o, 64);
    if ((threadIdx.x & 63) == 0) atomicAdd(&s_bad, cnt);
    __syncthreads();
    const int f32 = (s_bad > 4);
    if (blockIdx.x == 0 && threadIdx.x == 0) flag[0] = f32;

    const int T0 = (M * 1024) / 8;
    const int T1 = 4096 * 128;
    const int T2 = 1024 * 512;
    const int TB = (4096 + 1024) / 8;
    const int total = T0 + T1 + T2 + TB;
    const int t = blockIdx.x * 256 + threadIdx.x;
    const int stride = gridDim.x * 256;

    for (int i = t; i < total; i += stride) {
        if (i < T0) {
            bf16x8 o;
            if (f32) {
                const float4* p = (const float4*)x;
                float4 a = p[2 * i], b = p[2 * i + 1];
                o[0] = (bf16_t)a.x; o[1] = (bf16_t)a.y; o[2] = (bf16_t)a.z; o[3] = (bf16_t)a.w;
                o[4] = (bf16_t)b.x; o[5] = (bf16_t)b.y; o[6] = (bf16_t)b.z; o[7] = (bf16_t)b.w;
            } else {
                o = ((const bf16x8*)x)[i];
            }
            *(bf16x8*)(xb + (size_t)i * 8) = o;
        } else if (i < T0 + T1 + T2) {
            int g2 = (i >= T0 + T1);
            int ii = g2 ? (i - T0 - T1) : (i - T0);
            int rows = g2 ? 1024 : 4096;
            int logsub = g2 ? 9 : 7;
            int sub = 1 << logsub;
            const int* idx = g2 ? idx2 : idx1;
            const void* cb = g2 ? cb2 : cb1;
            bf16_t* W = g2 ? w2b : w1b;
            int r = ii >> logsub;
            int col = (ii & (sub - 1)) << 3;
            int c = col >> logsub;
            int j = col & (sub - 1);
            int code = idx[c * rows + r];
            size_t src = ((size_t)(c * 256 + code) << logsub) + j;
            bf16x8 o;
            if (f32) {
                const float* s = (const float*)cb + src;
                float4 a = *(const float4*)s;
                float4 b = *(const float4*)(s + 4);
                o[0] = (bf16_t)a.x; o[1] = (bf16_t)a.y; o[2] = (bf16_t)a.z; o[3] = (bf16_t)a.w;
                o[4] = (bf16_t)b.x; o[5] = (bf16_t)b.y; o[6] = (bf16_t)b.z; o[7] = (bf16_t)b.w;
            } else {
                o = *(const bf16x8*)((const bf16_t*)cb + src);
            }
            *(bf16x8*)(W + (size_t)r * ((size_t)sub << 3) + col) = o;
        } else {
            int g = i - (T0 + T1 + T2);
#pragma unroll
            for (int j = 0; j < 8; ++j) {
                int e = g * 8 + j;
                float v;
                const void* src = (e < 4096) ? b1 : b2;
                int k = (e < 4096) ? e : e - 4096;
                v = f32 ? ((const float*)src)[k] : (float)(((const bf16_t*)src)[k]);
                if (e < 4096) b1f[k] = v; else b2f[k] = v;
            }
        }
    }
}

// ---------------- GEMM: C[m,n] = sum_k A[m,k]*Bw[n,k] + bias[n] (opt gelu) ------
// Exact R3 inner structure (measured: 0 conflicts, VALU 15%, 89.3 us): BK=64,
// 8-chunk XOR swizzle on 64-wide LDS rows, precomputed frag pointers.
// XCDSW template flag A/Bs the XCD-band block swizzle (R5/R6: FETCH 266->50 MB,
// but time effect confounded — GEMM1 runs without, GEMM2 with, this round).
template <bool XCDSW, bool GELU, bool DYNOUT>
__global__ __launch_bounds__(256, 2)
void gemm_bt(const bf16_t* __restrict__ A, const bf16_t* __restrict__ Bw,
             const float* __restrict__ bias,
             bf16_t* __restrict__ obf, float* __restrict__ of32,
             int M, int N, int K, const int* __restrict__ flag) {
    __shared__ __attribute__((aligned(16))) bf16_t sA[128 * 64];
    __shared__ __attribute__((aligned(16))) bf16_t sB[128 * 64];

    const int tid = threadIdx.x;

    int bm, bn;
    if (XCDSW) {
        // xcd = l&7 owns a contiguous bm-band and sweeps bn; the blocks sharing
        // a B-tile are consecutive l on the SAME XCD (gridDim.y % 8 == 0).
        const int l = blockIdx.y * gridDim.x + blockIdx.x;
        const int xcd = l & 7;
        const int i = l >> 3;
        const int per = gridDim.y >> 3;
        bm = (xcd * per + (i % per)) << 7;
        bn = (i / per) << 7;
    } else {
        bm = blockIdx.y << 7;
        bn = blockIdx.x << 7;
    }

    // staging: thread t -> slot t (16B); row = p*32 + t>>3, swizzled k-chunk
    const int row0 = tid >> 3;                  // 0..31
    const int kc0 = ((tid & 7) - row0) & 7;     // pass-invariant (32 % 8 == 0)
    const bf16_t* gA = A + (size_t)(bm + row0) * K + kc0 * 8;
    const bf16_t* gB = Bw + (size_t)(bn + row0) * K + kc0 * 8;
    bf16_t* lA = sA + tid * 8;
    bf16_t* lB = sB + tid * 8;
    const size_t pskip = (size_t)32 * K;

    const int lane = tid & 63;
    const int wave = tid >> 6;
    const int quad = lane >> 4;
    const int lr = lane & 15;
    const int wm = (wave & 1) << 6;
    const int wn = (wave >> 1) << 6;

    const int arow = wm + lr;
    const int brow = wn + lr;
    const bf16x8* pA0 = (const bf16x8*)(sA + arow * 64 + ((quad + arow) & 7) * 8);
    const bf16x8* pA1 = (const bf16x8*)(sA + arow * 64 + ((quad + 4 + arow) & 7) * 8);
    const bf16x8* pB0 = (const bf16x8*)(sB + brow * 64 + ((quad + brow) & 7) * 8);
    const bf16x8* pB1 = (const bf16x8*)(sB + brow * 64 + ((quad + 4 + brow) & 7) * 8);

    f32x4 acc[4][4] = {};

    for (int k0 = 0; k0 < K; k0 += 64) {
#pragma unroll
        for (int p = 0; p < 4; ++p) g2l16(gA + p * pskip + k0, lA + p * 2048);
#pragma unroll
        for (int p = 0; p < 4; ++p) g2l16(gB + p * pskip + k0, lB + p * 2048);
        __syncthreads();

        bf16x8 af[4], bf[4];
#pragma unroll
        for (int f = 0; f < 4; ++f) { af[f] = pA0[f * 128]; bf[f] = pB0[f * 128]; }
#pragma unroll
        for (int mi = 0; mi < 4; ++mi)
#pragma unroll
            for (int ni = 0; ni < 4; ++ni)
                acc[mi][ni] = __builtin_amdgcn_mfma_f32_16x16x32_bf16(
                    af[mi], bf[ni], acc[mi][ni], 0, 0, 0);
#pragma unroll
        for (int f = 0; f < 4; ++f) { af[f] = pA1[f * 128]; bf[f] = pB1[f * 128]; }
#pragma unroll
        for (int mi = 0; mi < 4; ++mi)
#pragma unroll
            for (int ni = 0; ni < 4; ++ni)
                acc[mi][ni] = __builtin_amdgcn_mfma_f32_16x16x32_bf16(
                    af[mi], bf[ni], acc[mi][ni], 0, 0, 0);
        __syncthreads();
    }

    const int outf32 = DYNOUT ? *flag : 0;
#pragma unroll
    for (int mi = 0; mi < 4; ++mi) {
#pragma unroll
        for (int ni = 0; ni < 4; ++ni) {
            const int n = bn + wn + ni * 16 + lr;
            const float bs = bias[n];
            f32x4 v = acc[mi][ni];
#pragma unroll
            for (int r = 0; r < 4; ++r) {
                const int m = bm + wm + mi * 16 + quad * 4 + r;
                float val = v[r] + bs;
                if (GELU) val = 0.5f * val * (1.0f + erff(val * 0.70710678118654752f));
                const size_t o = (size_t)m * N + n;
                if (DYNOUT) {
                    if (outf32) of32[o] = val;
                    else        obf[o] = (bf16_t)val;
                } else {
                    obf[o] = (bf16_t)val;
                }
            }
        }
    }
}

// ---------------- launch ----------------
extern "C" void kernel_launch(void* const* d_in, const int* in_sizes, int n_in,
                              void* d_out, int out_size, void* d_ws, size_t ws_size,
                              hipStream_t stream) {
    const void* x   = d_in[0];
    const void* cb1 = d_in[1];
    const int*  idx1 = (const int*)d_in[2];
    const void* b1  = d_in[3];
    const void* cb2 = d_in[4];
    const int*  idx2 = (const int*)d_in[5];
    const void* b2  = d_in[6];

    const int D = 1024, H = 4096;
    const int M = in_sizes[0] / D;     // 8192

    char* ws = (char*)d_ws;
    bf16_t* xb  = (bf16_t*)ws;                                   // M*D bf16 (16 MB)
    bf16_t* w1b = (bf16_t*)(ws + (size_t)M * D * 2);             // H*D bf16 (8 MB)
    bf16_t* hb  = (bf16_t*)((char*)w1b + (size_t)H * D * 2);     // M*H bf16 (64 MB)
    bf16_t* w2b = (bf16_t*)((char*)hb + (size_t)M * H * 2);      // D*H bf16 (8 MB)
    float*  b1f = (float*)((char*)w2b + (size_t)D * H * 2);      // H f32
    float*  b2f = b1f + H;                                       // D f32
    int*    flag = (int*)(b2f + D);

    prep_all<<<2048, 256, 0, stream>>>(x, cb1, idx1, b1, cb2, idx2, b2,
                                       xb, w1b, w2b, b1f, b2f, flag, M);

    // Cell A: exact R3 (no XCD swizzle)
    dim3 g1(H / 128, M / 128);   // (32, 64)
    gemm_bt<false, true, false><<<g1, 256, 0, stream>>>(xb, w1b, b1f, hb, nullptr, M, H, D, flag);

    // Cell B: R3 + XCD swizzle
    dim3 g2(D / 128, M / 128);   // (8, 64)
    gemm_bt<true, false, true><<<g2, 256, 0, stream>>>(hb, w2b, b2f, (bf16_t*)d_out, (float*)d_out, M, D, H, flag);
}